// Round 1
// baseline (7573.198 us; speedup 1.0000x reference)
//
#include <hip/hip_runtime.h>
#include <hip/hip_bf16.h>

#define BATCH 2048
#define TSEQ  64
#define DIN   512
#define HID   1024
#define CIN   1536   // DIN + HID

#define BM 128
#define BN 64
#define BK 64
#define LDA 72       // BK + 8 bf16 pad -> 144B row stride, 2-way bank aliasing only (free)

typedef __attribute__((ext_vector_type(8))) short bf16x8;
typedef __attribute__((ext_vector_type(4))) float f32x4;

// RNE float -> bf16 (bits)
__device__ __forceinline__ unsigned short f2bf(float f) {
    unsigned int u = __float_as_uint(f);
    u += 0x7fffu + ((u >> 16) & 1u);
    return (unsigned short)(u >> 16);
}
__device__ __forceinline__ float bf2f(unsigned short u) {
    return __uint_as_float(((unsigned int)u) << 16);
}

// ---------------- weight conversion: fp32 -> bf16, 3 matrices [HID][CIN] ----------------
__global__ __launch_bounds__(256) void convert_w(const float* __restrict__ Wf,
                                                 const float* __restrict__ Wg,
                                                 const float* __restrict__ Wh,
                                                 unsigned short* __restrict__ Wb) {
    int mat = blockIdx.y;
    const float* src = (mat == 0) ? Wf : ((mat == 1) ? Wg : Wh);
    size_t base = (size_t)mat * (size_t)(HID * CIN);
    size_t idx = ((size_t)blockIdx.x * 256 + threadIdx.x) * 8;   // 768 blocks * 256 thr * 8 = 1572864
    const float4* s = (const float4*)(src + idx);
    float4 a = s[0], b = s[1];
    uint4 o;
    o.x = (unsigned)f2bf(a.x) | ((unsigned)f2bf(a.y) << 16);
    o.y = (unsigned)f2bf(a.z) | ((unsigned)f2bf(a.w) << 16);
    o.z = (unsigned)f2bf(b.x) | ((unsigned)f2bf(b.y) << 16);
    o.w = (unsigned)f2bf(b.z) | ((unsigned)f2bf(b.w) << 16);
    *(uint4*)(Wb + base + idx) = o;
}

// ---------------- one recurrence step: fused 3xGEMM + gate ----------------
// A = [x_t (fp32, cols 0..511) | h_in (bf16, cols 512..1535)]  [2048 x 1536]
// B_mat = W_mat^T i.e. lds holds W[n][k] rows               -> C = A @ W^T
// epilogue: gate = sigmoid(-f); h_out = gate*g + (1-gate)*h   (bf16)
__global__ __launch_bounds__(256, 1) void step_kernel(
    const float* __restrict__ x,
    const unsigned short* __restrict__ Wb,     // bf16 bits, 3*HID*CIN
    const float* __restrict__ bfv,
    const float* __restrict__ bgv,
    const float* __restrict__ bhv,
    const unsigned short* __restrict__ hin,    // bf16 bits [BATCH][HID]
    unsigned short* __restrict__ hout,         // bf16 bits [BATCH][HID]
    int t)
{
    __shared__ __align__(16) unsigned short As[BM][LDA];       // 18432 B
    __shared__ __align__(16) unsigned short Bs[3][BN][LDA];    // 27648 B

    const int tid  = threadIdx.x;
    const int bid  = blockIdx.x;
    // XCD-friendly: blocks with same (bid&7) share N-columns -> weight tiles stay in that XCD's L2
    const int n_tile = ((bid & 7) << 1) | ((bid >> 3) & 1);
    const int m_tile = bid >> 4;
    const int m0 = m_tile * BM;
    const int n0 = n_tile * BN;

    const int lane = tid & 63;
    const int wave = tid >> 6;
    const int wm = wave >> 1;      // 0..1 : M half
    const int wn = wave & 1;       // 0..1 : N half

    // staging thread mapping: 8 lanes per 64-col row (16B each)
    const int srow = tid >> 3;          // 0..31
    const int scol = (tid & 7) * 8;     // elem col 0,8,..,56

    f32x4 acc[3][4][2] = {};

    // per-column biases (depend only on lane&15 / nt)
    float biasF[2], biasG[2], biasH[2];
#pragma unroll
    for (int nt = 0; nt < 2; ++nt) {
        int cg = n0 + wn * 32 + nt * 16 + (lane & 15);
        biasF[nt] = bfv[cg];
        biasG[nt] = bgv[cg];
        biasH[nt] = bhv[cg];
    }

    // prefetch registers
    float4 axr[4][2];
    uint4  ahr[4];
    uint4  bwr[3][2];

    auto loadA = [&](int ki) {
        int k0 = ki * BK;
        if (k0 < DIN) {
#pragma unroll
            for (int i = 0; i < 4; ++i) {
                int row = srow + i * 32;
                const float* p = x + ((size_t)(m0 + row) * TSEQ + t) * DIN + k0 + scol;
                axr[i][0] = *(const float4*)p;
                axr[i][1] = *(const float4*)(p + 4);
            }
        } else {
            int kh = k0 - DIN;
#pragma unroll
            for (int i = 0; i < 4; ++i) {
                int row = srow + i * 32;
                ahr[i] = *(const uint4*)(hin + (size_t)(m0 + row) * HID + kh + scol);
            }
        }
    };
    auto loadB = [&](int ki) {
        int k0 = ki * BK;
#pragma unroll
        for (int mat = 0; mat < 3; ++mat)
#pragma unroll
            for (int i = 0; i < 2; ++i) {
                int row = srow + i * 32;
                bwr[mat][i] = *(const uint4*)(Wb + (size_t)mat * (HID * CIN)
                                              + (size_t)(n0 + row) * CIN + k0 + scol);
            }
    };
    auto writeA = [&](int ki) {
        int k0 = ki * BK;
        if (k0 < DIN) {
#pragma unroll
            for (int i = 0; i < 4; ++i) {
                int row = srow + i * 32;
                uint4 o;
                o.x = (unsigned)f2bf(axr[i][0].x) | ((unsigned)f2bf(axr[i][0].y) << 16);
                o.y = (unsigned)f2bf(axr[i][0].z) | ((unsigned)f2bf(axr[i][0].w) << 16);
                o.z = (unsigned)f2bf(axr[i][1].x) | ((unsigned)f2bf(axr[i][1].y) << 16);
                o.w = (unsigned)f2bf(axr[i][1].z) | ((unsigned)f2bf(axr[i][1].w) << 16);
                *(uint4*)&As[row][scol] = o;
            }
        } else {
#pragma unroll
            for (int i = 0; i < 4; ++i)
                *(uint4*)&As[srow + i * 32][scol] = ahr[i];
        }
    };
    auto writeB = [&]() {
#pragma unroll
        for (int mat = 0; mat < 3; ++mat)
#pragma unroll
            for (int i = 0; i < 2; ++i)
                *(uint4*)&Bs[mat][srow + i * 32][scol] = bwr[mat][i];
    };

    auto compute = [&]() {
#pragma unroll
        for (int ks = 0; ks < 2; ++ks) {
            bf16x8 af[4];
#pragma unroll
            for (int mt = 0; mt < 4; ++mt)
                af[mt] = *(const bf16x8*)&As[wm * 64 + mt * 16 + (lane & 15)]
                                           [ks * 32 + (lane >> 4) * 8];
#pragma unroll
            for (int mat = 0; mat < 3; ++mat) {
                bf16x8 bq[2];
#pragma unroll
                for (int nt = 0; nt < 2; ++nt)
                    bq[nt] = *(const bf16x8*)&Bs[mat][wn * 32 + nt * 16 + (lane & 15)]
                                               [ks * 32 + (lane >> 4) * 8];
#pragma unroll
                for (int mt = 0; mt < 4; ++mt)
#pragma unroll
                    for (int nt = 0; nt < 2; ++nt)
                        acc[mat][mt][nt] = __builtin_amdgcn_mfma_f32_16x16x32_bf16(
                            af[mt], bq[nt], acc[mat][mt][nt], 0, 0, 0);
            }
        }
    };

    // prologue: stage tile 0
    loadA(0); loadB(0);
    writeA(0); writeB();
    __syncthreads();

    const int KITERS = CIN / BK;   // 24
    for (int ki = 0; ki < KITERS; ++ki) {
        if (ki < KITERS - 1) { loadA(ki + 1); loadB(ki + 1); }  // in flight during compute
        compute();
        __syncthreads();                                        // all waves done reading LDS
        if (ki < KITERS - 1) { writeA(ki + 1); writeB(); __syncthreads(); }
    }

    // epilogue: gate + write bf16 h_out
    // C/D layout (16x16x32): col = lane&15, row = (lane>>4)*4 + reg   [m89-verified]
#pragma unroll
    for (int mt = 0; mt < 4; ++mt) {
        int rbase = m0 + wm * 64 + mt * 16 + (lane >> 4) * 4;
#pragma unroll
        for (int nt = 0; nt < 2; ++nt) {
            int cg = n0 + wn * 32 + nt * 16 + (lane & 15);
#pragma unroll
            for (int r = 0; r < 4; ++r) {
                float f  = acc[0][mt][nt][r] + biasF[nt];
                float g  = acc[1][mt][nt][r] + biasG[nt];
                float hh = acc[2][mt][nt][r] + biasH[nt];
                float gate = 1.0f / (1.0f + __expf(f));   // sigmoid(-f)
                float nh = hh + gate * (g - hh);
                hout[(size_t)(rbase + r) * HID + cg] = f2bf(nh);
            }
        }
    }
}

// ---------------- final FC: out[2048][2] = h @ Wfc^T + bfc ----------------
__global__ __launch_bounds__(256) void fc_kernel(const unsigned short* __restrict__ h,
                                                 const float* __restrict__ Wfc,
                                                 const float* __restrict__ bfc,
                                                 float* __restrict__ out) {
    int row = blockIdx.x;
    int tid = threadIdx.x;
    const unsigned short* hr = h + (size_t)row * HID;
    ushort4 hv = *(const ushort4*)(hr + tid * 4);
    float h0 = bf2f(hv.x), h1 = bf2f(hv.y), h2 = bf2f(hv.z), h3 = bf2f(hv.w);
    float4 w0 = *(const float4*)(Wfc + tid * 4);
    float4 w1 = *(const float4*)(Wfc + HID + tid * 4);
    float a0 = h0 * w0.x + h1 * w0.y + h2 * w0.z + h3 * w0.w;
    float a1 = h0 * w1.x + h1 * w1.y + h2 * w1.z + h3 * w1.w;
#pragma unroll
    for (int off = 32; off > 0; off >>= 1) {
        a0 += __shfl_down(a0, off);
        a1 += __shfl_down(a1, off);
    }
    __shared__ float red[2][4];
    if ((tid & 63) == 0) { red[0][tid >> 6] = a0; red[1][tid >> 6] = a1; }
    __syncthreads();
    if (tid == 0) out[(size_t)row * 2 + 0] = red[0][0] + red[0][1] + red[0][2] + red[0][3] + bfc[0];
    if (tid == 1) out[(size_t)row * 2 + 1] = red[1][0] + red[1][1] + red[1][2] + red[1][3] + bfc[1];
}

extern "C" void kernel_launch(void* const* d_in, const int* in_sizes, int n_in,
                              void* d_out, int out_size, void* d_ws, size_t ws_size,
                              hipStream_t stream) {
    const float* x   = (const float*)d_in[0];
    const float* Wf  = (const float*)d_in[1];
    const float* bfv = (const float*)d_in[2];
    const float* Wg  = (const float*)d_in[3];
    const float* bgv = (const float*)d_in[4];
    const float* Wh  = (const float*)d_in[5];
    const float* bhv = (const float*)d_in[6];
    const float* Wfc = (const float*)d_in[7];
    const float* bfc = (const float*)d_in[8];
    float* out = (float*)d_out;

    char* ws = (char*)d_ws;
    unsigned short* Wb = (unsigned short*)ws;                       // 3*HID*CIN bf16 = 9437184 B
    size_t wb_bytes = (size_t)3 * HID * CIN * 2;
    size_t h_bytes  = (size_t)BATCH * HID * 2;                      // 4194304 B
    unsigned short* h0 = (unsigned short*)(ws + wb_bytes);
    unsigned short* h1 = (unsigned short*)(ws + wb_bytes + h_bytes);
    // total ws use: ~17.8 MB

    convert_w<<<dim3(768, 3), 256, 0, stream>>>(Wf, Wg, Wh, Wb);
    hipMemsetAsync(h0, 0, h_bytes, stream);                         // h_0 = 0 (capturable)

    unsigned short* bufs[2] = {h0, h1};
    for (int t = 0; t < TSEQ; ++t) {
        step_kernel<<<256, 256, 0, stream>>>(x, Wb, bfv, bgv, bhv,
                                             bufs[t & 1], bufs[(t + 1) & 1], t);
    }
    // after 64 steps, final h is in bufs[0]
    fc_kernel<<<BATCH, 256, 0, stream>>>(h0, Wfc, bfc, out);
}

// Round 3
// 4511.737 us; speedup vs baseline: 1.6786x; 1.6786x over previous
//
#include <hip/hip_runtime.h>
#include <hip/hip_bf16.h>

#define BATCH 2048
#define TSEQ  64
#define DIN   512
#define HID   1024
#define CIN   1536   // DIN + HID

#define BM 128
#define BN 64
#define BK 64
#define LDA 72       // BK + 8 bf16 pad -> 144B row stride, 2-way bank aliasing only (free)

typedef __attribute__((ext_vector_type(8))) short bf16x8;
typedef __attribute__((ext_vector_type(4))) float f32x4;
typedef __attribute__((ext_vector_type(4))) float fvec4;          // clang ext vector: OK for NT builtins
typedef __attribute__((ext_vector_type(4))) unsigned int uvec4;   // clang ext vector: OK for NT builtins

// RNE float -> bf16 (bits)
__device__ __forceinline__ unsigned short f2bf(float f) {
    unsigned int u = __float_as_uint(f);
    u += 0x7fffu + ((u >> 16) & 1u);
    return (unsigned short)(u >> 16);
}
__device__ __forceinline__ float bf2f(unsigned short u) {
    return __uint_as_float(((unsigned int)u) << 16);
}

// ---------------- weight conversion: fp32 -> bf16, 3 matrices [HID][CIN] ----------------
__global__ __launch_bounds__(256) void convert_w(const float* __restrict__ Wf,
                                                 const float* __restrict__ Wg,
                                                 const float* __restrict__ Wh,
                                                 unsigned short* __restrict__ Wb) {
    int mat = blockIdx.y;
    const float* src = (mat == 0) ? Wf : ((mat == 1) ? Wg : Wh);
    size_t base = (size_t)mat * (size_t)(HID * CIN);
    size_t idx = ((size_t)blockIdx.x * 256 + threadIdx.x) * 8;   // 768 blocks * 256 thr * 8 = 1572864
    const fvec4* s = (const fvec4*)(src + idx);
    fvec4 a = s[0], b = s[1];
    uvec4 o;
    o.x = (unsigned)f2bf(a.x) | ((unsigned)f2bf(a.y) << 16);
    o.y = (unsigned)f2bf(a.z) | ((unsigned)f2bf(a.w) << 16);
    o.z = (unsigned)f2bf(b.x) | ((unsigned)f2bf(b.y) << 16);
    o.w = (unsigned)f2bf(b.z) | ((unsigned)f2bf(b.w) << 16);
    *(uvec4*)(Wb + base + idx) = o;
}

// ---------------- one recurrence step: fused 3xGEMM + gate ----------------
// A = [x_t (fp32, cols 0..511) | h_in (bf16, cols 512..1535)]  [2048 x 1536]  -- NT loads
// B_mat = W_mat^T (lds holds W[n][k] rows, temporal -> L2-resident per XCD)   -> C = A @ W^T
// epilogue: gate = sigmoid(-f); h_out = gate*g + (1-gate)*h   (bf16, NT store)
__global__ __launch_bounds__(256, 1) void step_kernel(
    const float* __restrict__ x,
    const unsigned short* __restrict__ Wb,     // bf16 bits, 3*HID*CIN
    const float* __restrict__ bfv,
    const float* __restrict__ bgv,
    const float* __restrict__ bhv,
    const unsigned short* __restrict__ hin,    // bf16 bits [BATCH][HID]
    unsigned short* __restrict__ hout,         // bf16 bits [BATCH][HID]
    int t)
{
    __shared__ __align__(16) unsigned short As[BM][LDA];       // 18432 B
    __shared__ __align__(16) unsigned short Bs[3][BN][LDA];    // 27648 B

    const int tid  = threadIdx.x;
    const int bid  = blockIdx.x;
    // XCD-friendly: blocks with same (bid&7) share N-columns -> weight tiles stay in that XCD's L2
    const int n_tile = ((bid & 7) << 1) | ((bid >> 3) & 1);
    const int m_tile = bid >> 4;
    const int m0 = m_tile * BM;
    const int n0 = n_tile * BN;

    const int lane = tid & 63;
    const int wave = tid >> 6;
    const int wm = wave >> 1;      // 0..1 : M half
    const int wn = wave & 1;       // 0..1 : N half

    // staging thread mapping: 8 lanes per 64-col row (16B each)
    const int srow = tid >> 3;          // 0..31
    const int scol = (tid & 7) * 8;     // elem col 0,8,..,56

    f32x4 acc[3][4][2] = {};

    // per-column biases (depend only on lane&15 / nt)
    float biasF[2], biasG[2], biasH[2];
#pragma unroll
    for (int nt = 0; nt < 2; ++nt) {
        int cg = n0 + wn * 32 + nt * 16 + (lane & 15);
        biasF[nt] = bfv[cg];
        biasG[nt] = bgv[cg];
        biasH[nt] = bhv[cg];
    }

    // prefetch registers
    fvec4 axr[4][2];
    uvec4 ahr[4];
    uvec4 bwr[3][2];

    auto loadA = [&](int ki) {
        int k0 = ki * BK;
        if (k0 < DIN) {
#pragma unroll
            for (int i = 0; i < 4; ++i) {
                int row = srow + i * 32;
                const float* p = x + ((size_t)(m0 + row) * TSEQ + t) * DIN + k0 + scol;
                axr[i][0] = __builtin_nontemporal_load((const fvec4*)p);
                axr[i][1] = __builtin_nontemporal_load((const fvec4*)(p + 4));
            }
        } else {
            int kh = k0 - DIN;
#pragma unroll
            for (int i = 0; i < 4; ++i) {
                int row = srow + i * 32;
                ahr[i] = __builtin_nontemporal_load(
                    (const uvec4*)(hin + (size_t)(m0 + row) * HID + kh + scol));
            }
        }
    };
    auto loadB = [&](int ki) {
        int k0 = ki * BK;
#pragma unroll
        for (int mat = 0; mat < 3; ++mat)
#pragma unroll
            for (int i = 0; i < 2; ++i) {
                int row = srow + i * 32;
                bwr[mat][i] = *(const uvec4*)(Wb + (size_t)mat * (HID * CIN)
                                              + (size_t)(n0 + row) * CIN + k0 + scol);
            }
    };
    auto writeA = [&](int ki) {
        int k0 = ki * BK;
        if (k0 < DIN) {
#pragma unroll
            for (int i = 0; i < 4; ++i) {
                int row = srow + i * 32;
                uvec4 o;
                o.x = (unsigned)f2bf(axr[i][0].x) | ((unsigned)f2bf(axr[i][0].y) << 16);
                o.y = (unsigned)f2bf(axr[i][0].z) | ((unsigned)f2bf(axr[i][0].w) << 16);
                o.z = (unsigned)f2bf(axr[i][1].x) | ((unsigned)f2bf(axr[i][1].y) << 16);
                o.w = (unsigned)f2bf(axr[i][1].z) | ((unsigned)f2bf(axr[i][1].w) << 16);
                *(uvec4*)&As[row][scol] = o;
            }
        } else {
#pragma unroll
            for (int i = 0; i < 4; ++i)
                *(uvec4*)&As[srow + i * 32][scol] = ahr[i];
        }
    };
    auto writeB = [&]() {
#pragma unroll
        for (int mat = 0; mat < 3; ++mat)
#pragma unroll
            for (int i = 0; i < 2; ++i)
                *(uvec4*)&Bs[mat][srow + i * 32][scol] = bwr[mat][i];
    };

    auto compute = [&]() {
#pragma unroll
        for (int ks = 0; ks < 2; ++ks) {
            bf16x8 af[4];
#pragma unroll
            for (int mt = 0; mt < 4; ++mt)
                af[mt] = *(const bf16x8*)&As[wm * 64 + mt * 16 + (lane & 15)]
                                           [ks * 32 + (lane >> 4) * 8];
#pragma unroll
            for (int mat = 0; mat < 3; ++mat) {
                bf16x8 bq[2];
#pragma unroll
                for (int nt = 0; nt < 2; ++nt)
                    bq[nt] = *(const bf16x8*)&Bs[mat][wn * 32 + nt * 16 + (lane & 15)]
                                               [ks * 32 + (lane >> 4) * 8];
#pragma unroll
                for (int mt = 0; mt < 4; ++mt)
#pragma unroll
                    for (int nt = 0; nt < 2; ++nt)
                        acc[mat][mt][nt] = __builtin_amdgcn_mfma_f32_16x16x32_bf16(
                            af[mt], bq[nt], acc[mat][mt][nt], 0, 0, 0);
            }
        }
    };

    // prologue: stage tile 0
    loadA(0); loadB(0);
    writeA(0); writeB();
    __syncthreads();

    const int KITERS = CIN / BK;   // 24
    for (int ki = 0; ki < KITERS; ++ki) {
        if (ki < KITERS - 1) { loadA(ki + 1); loadB(ki + 1); }  // in flight during compute
        compute();
        __syncthreads();                                        // all waves done reading LDS
        if (ki < KITERS - 1) { writeA(ki + 1); writeB(); __syncthreads(); }
    }

    // epilogue: gate + write bf16 h_out (non-temporal: streamed, read once next step)
    // C/D layout (16x16x32): col = lane&15, row = (lane>>4)*4 + reg   [m89-verified]
#pragma unroll
    for (int mt = 0; mt < 4; ++mt) {
        int rbase = m0 + wm * 64 + mt * 16 + (lane >> 4) * 4;
#pragma unroll
        for (int nt = 0; nt < 2; ++nt) {
            int cg = n0 + wn * 32 + nt * 16 + (lane & 15);
#pragma unroll
            for (int r = 0; r < 4; ++r) {
                float f  = acc[0][mt][nt][r] + biasF[nt];
                float g  = acc[1][mt][nt][r] + biasG[nt];
                float hh = acc[2][mt][nt][r] + biasH[nt];
                float gate = 1.0f / (1.0f + __expf(f));   // sigmoid(-f)
                float nh = hh + gate * (g - hh);
                __builtin_nontemporal_store(f2bf(nh),
                    hout + (size_t)(rbase + r) * HID + cg);
            }
        }
    }
}

// ---------------- final FC: out[2048][2] = h @ Wfc^T + bfc ----------------
__global__ __launch_bounds__(256) void fc_kernel(const unsigned short* __restrict__ h,
                                                 const float* __restrict__ Wfc,
                                                 const float* __restrict__ bfc,
                                                 float* __restrict__ out) {
    int row = blockIdx.x;
    int tid = threadIdx.x;
    const unsigned short* hr = h + (size_t)row * HID;
    ushort4 hv = *(const ushort4*)(hr + tid * 4);
    float h0 = bf2f(hv.x), h1 = bf2f(hv.y), h2 = bf2f(hv.z), h3 = bf2f(hv.w);
    float4 w0 = *(const float4*)(Wfc + tid * 4);
    float4 w1 = *(const float4*)(Wfc + HID + tid * 4);
    float a0 = h0 * w0.x + h1 * w0.y + h2 * w0.z + h3 * w0.w;
    float a1 = h0 * w1.x + h1 * w1.y + h2 * w1.z + h3 * w1.w;
#pragma unroll
    for (int off = 32; off > 0; off >>= 1) {
        a0 += __shfl_down(a0, off);
        a1 += __shfl_down(a1, off);
    }
    __shared__ float red[2][4];
    if ((tid & 63) == 0) { red[0][tid >> 6] = a0; red[1][tid >> 6] = a1; }
    __syncthreads();
    if (tid == 0) out[(size_t)row * 2 + 0] = red[0][0] + red[0][1] + red[0][2] + red[0][3] + bfc[0];
    if (tid == 1) out[(size_t)row * 2 + 1] = red[1][0] + red[1][1] + red[1][2] + red[1][3] + bfc[1];
}

extern "C" void kernel_launch(void* const* d_in, const int* in_sizes, int n_in,
                              void* d_out, int out_size, void* d_ws, size_t ws_size,
                              hipStream_t stream) {
    const float* x   = (const float*)d_in[0];
    const float* Wf  = (const float*)d_in[1];
    const float* bfv = (const float*)d_in[2];
    const float* Wg  = (const float*)d_in[3];
    const float* bgv = (const float*)d_in[4];
    const float* Wh  = (const float*)d_in[5];
    const float* bhv = (const float*)d_in[6];
    const float* Wfc = (const float*)d_in[7];
    const float* bfc = (const float*)d_in[8];
    float* out = (float*)d_out;

    char* ws = (char*)d_ws;
    unsigned short* Wb = (unsigned short*)ws;                       // 3*HID*CIN bf16 = 9437184 B
    size_t wb_bytes = (size_t)3 * HID * CIN * 2;
    size_t h_bytes  = (size_t)BATCH * HID * 2;                      // 4194304 B
    unsigned short* h0 = (unsigned short*)(ws + wb_bytes);
    unsigned short* h1 = (unsigned short*)(ws + wb_bytes + h_bytes);
    // total ws use: ~17.8 MB (harness ws is ~1 GiB per the fill dispatches)

    convert_w<<<dim3(768, 3), 256, 0, stream>>>(Wf, Wg, Wh, Wb);
    (void)hipMemsetAsync(h0, 0, h_bytes, stream);                   // h_0 = 0 (capturable)

    unsigned short* bufs[2] = {h0, h1};
    for (int t = 0; t < TSEQ; ++t) {
        step_kernel<<<256, 256, 0, stream>>>(x, Wb, bfv, bgv, bhv,
                                             bufs[t & 1], bufs[(t + 1) & 1], t);
    }
    // after 64 steps, final h is in bufs[0]
    fc_kernel<<<BATCH, 256, 0, stream>>>(h0, Wfc, bfc, out);
}

// Round 4
// 3572.973 us; speedup vs baseline: 2.1196x; 1.2627x over previous
//
#include <hip/hip_runtime.h>

#define BATCH 2048
#define TSEQ  64
#define DIN   512
#define HID   1024
#define CIN   1536   // DIN + HID

#define BM 64
#define BN 64
#define BK 128
#define KITERS (CIN / BK)   // 12

typedef __attribute__((ext_vector_type(8))) short bf16x8;
typedef __attribute__((ext_vector_type(4))) float f32x4;
typedef __attribute__((ext_vector_type(4))) float fvec4;
typedef __attribute__((ext_vector_type(4))) unsigned int uvec4;

// RNE float -> bf16 (bits)
__device__ __forceinline__ unsigned short f2bf(float f) {
    unsigned int u = __float_as_uint(f);
    u += 0x7fffu + ((u >> 16) & 1u);
    return (unsigned short)(u >> 16);
}
__device__ __forceinline__ float bf2f(unsigned short u) {
    return __uint_as_float(((unsigned int)u) << 16);
}

// async global->LDS, 16B per lane. ldsptr must be wave-uniform; lane i lands at +i*16.
// AS casts via integer detour (always-valid C++): global generic==AS1 numerically;
// LDS generic = 4GiB-aligned aperture | offset, so low 32 bits == LDS offset.
__device__ __forceinline__ void gload_lds16(const void* g, void* lds) {
    __builtin_amdgcn_global_load_lds(
        (const __attribute__((address_space(1))) void*)(uintptr_t)g,
        (__attribute__((address_space(3))) void*)(unsigned)(uintptr_t)lds,
        16, 0, 0);
}

// ---------------- weight conversion: fp32 -> bf16, 3 matrices [HID][CIN] ----------------
__global__ __launch_bounds__(256) void convert_w(const float* __restrict__ Wf,
                                                 const float* __restrict__ Wg,
                                                 const float* __restrict__ Wh,
                                                 unsigned short* __restrict__ Wb) {
    int mat = blockIdx.y;
    const float* src = (mat == 0) ? Wf : ((mat == 1) ? Wg : Wh);
    size_t base = (size_t)mat * (size_t)(HID * CIN);
    size_t idx = ((size_t)blockIdx.x * 256 + threadIdx.x) * 8;
    const fvec4* s = (const fvec4*)(src + idx);
    fvec4 a = s[0], b = s[1];
    uvec4 o;
    o.x = (unsigned)f2bf(a.x) | ((unsigned)f2bf(a.y) << 16);
    o.y = (unsigned)f2bf(a.z) | ((unsigned)f2bf(a.w) << 16);
    o.z = (unsigned)f2bf(b.x) | ((unsigned)f2bf(b.y) << 16);
    o.w = (unsigned)f2bf(b.z) | ((unsigned)f2bf(b.w) << 16);
    *(uvec4*)(Wb + base + idx) = o;
}

// ---------------- x conversion: [B][T][D] fp32 -> [T][B][D] bf16 (time-major) ----------------
__global__ __launch_bounds__(256) void convert_x(const float* __restrict__ x,
                                                 unsigned short* __restrict__ xb) {
    size_t e = ((size_t)blockIdx.x * 256 + threadIdx.x) * 8;   // out elem idx in [T][B][D]
    int t   = (int)(e / ((size_t)BATCH * DIN));
    int rem = (int)(e % ((size_t)BATCH * DIN));
    int b = rem / DIN;
    int d = rem % DIN;
    const float* src = x + ((size_t)b * TSEQ + t) * DIN + d;
    fvec4 a = *(const fvec4*)src;
    fvec4 c = *(const fvec4*)(src + 4);
    uvec4 o;
    o.x = (unsigned)f2bf(a.x) | ((unsigned)f2bf(a.y) << 16);
    o.y = (unsigned)f2bf(a.z) | ((unsigned)f2bf(a.w) << 16);
    o.z = (unsigned)f2bf(c.x) | ((unsigned)f2bf(c.y) << 16);
    o.w = (unsigned)f2bf(c.z) | ((unsigned)f2bf(c.w) << 16);
    *(uvec4*)(xb + e) = o;
}

// ---------------- one recurrence step: fused 3xGEMM + gate ----------------
// A = [xb_t | h_in] (all bf16), staged via global_load_lds width=16 (no reg round-trip).
// Weights temporal (n-affinity -> per-XCD L2-resident slice). Grid 512 = 2 blocks/CU.
__global__ __launch_bounds__(256, 2) void step_kernel(
    const unsigned short* __restrict__ xb,     // bf16 [TSEQ][BATCH][DIN]
    const unsigned short* __restrict__ Wb,     // bf16 [3][HID][CIN]
    const float* __restrict__ bfv,
    const float* __restrict__ bgv,
    const float* __restrict__ bhv,
    const unsigned short* __restrict__ hin,    // bf16 [BATCH][HID]
    unsigned short* __restrict__ hout,         // bf16 [BATCH][HID]
    int t)
{
    __shared__ __align__(16) unsigned short As[BM][BK];       // 16 KB, unpadded (LDS-DMA layout)
    __shared__ __align__(16) unsigned short Bs[3][BN][BK];    // 48 KB

    const int tid  = threadIdx.x;
    const int bid  = blockIdx.x;
    // n-affinity XCD swizzle: XCD = bid&7 gets n_tiles {2j,2j+1} -> 1.18 MB weights L2-resident
    const int n_tile = ((bid & 7) << 1) | ((bid >> 3) & 1);   // 0..15
    const int m_tile = bid >> 4;                              // 0..31
    const int m0 = m_tile * BM;
    const int n0 = n_tile * BN;

    const int lane = tid & 63;
    const int wave = tid >> 6;
    const int wm = wave >> 1;      // 0..1 : 32-row half
    const int wn = wave & 1;       // 0..1 : 32-col half

    // staging lane mapping within a 4-row x 256B chunk
    const int crow = lane >> 4;          // 0..3
    const int ccol = (lane & 15) * 8;    // elem col (16B per lane)

    f32x4 acc[3][2][2] = {};

    float biasF[2], biasG[2], biasH[2];
#pragma unroll
    for (int nt = 0; nt < 2; ++nt) {
        int cg = n0 + wn * 32 + nt * 16 + (lane & 15);
        biasF[nt] = bfv[cg];
        biasG[nt] = bgv[cg];
        biasH[nt] = bhv[cg];
    }

    const unsigned short* xsrc = xb + (size_t)t * BATCH * DIN;

    for (int ki = 0; ki < KITERS; ++ki) {
        const int k0 = ki * BK;
        // ---- stage A: 16 KB = 16 chunks, wave w does rows [w*16, w*16+16) ----
        const unsigned short* asrc;
        int astride;
        if (k0 < DIN) { asrc = xsrc + k0;        astride = DIN; }   // ki 0..3
        else          { asrc = hin + (k0 - DIN); astride = HID; }   // ki 4..11
#pragma unroll
        for (int c = 0; c < 4; ++c) {
            int rbase = wave * 16 + c * 4;
            gload_lds16(asrc + (size_t)(m0 + rbase + crow) * astride + ccol,
                        &As[rbase][0]);
        }
        // ---- stage B: 3 x 16 KB ----
#pragma unroll
        for (int mat = 0; mat < 3; ++mat) {
            const unsigned short* bsrc = Wb + (size_t)mat * (HID * CIN) + k0;
#pragma unroll
            for (int c = 0; c < 4; ++c) {
                int rbase = wave * 16 + c * 4;
                gload_lds16(bsrc + (size_t)(n0 + rbase + crow) * CIN + ccol,
                            &Bs[mat][rbase][0]);
            }
        }
        __syncthreads();   // compiler drains vmcnt(0) before barrier -> tiles ready

        // ---- compute: 4 k-steps of 32, 12 MFMA each ----
#pragma unroll
        for (int s = 0; s < 4; ++s) {
            const int kb = s * 32 + (lane >> 4) * 8;
            bf16x8 af0 = *(const bf16x8*)&As[wm * 32 +      (lane & 15)][kb];
            bf16x8 af1 = *(const bf16x8*)&As[wm * 32 + 16 + (lane & 15)][kb];
#pragma unroll
            for (int mat = 0; mat < 3; ++mat) {
                bf16x8 b0 = *(const bf16x8*)&Bs[mat][wn * 32 +      (lane & 15)][kb];
                bf16x8 b1 = *(const bf16x8*)&Bs[mat][wn * 32 + 16 + (lane & 15)][kb];
                acc[mat][0][0] = __builtin_amdgcn_mfma_f32_16x16x32_bf16(af0, b0, acc[mat][0][0], 0, 0, 0);
                acc[mat][0][1] = __builtin_amdgcn_mfma_f32_16x16x32_bf16(af0, b1, acc[mat][0][1], 0, 0, 0);
                acc[mat][1][0] = __builtin_amdgcn_mfma_f32_16x16x32_bf16(af1, b0, acc[mat][1][0], 0, 0, 0);
                acc[mat][1][1] = __builtin_amdgcn_mfma_f32_16x16x32_bf16(af1, b1, acc[mat][1][1], 0, 0, 0);
            }
        }
        __syncthreads();   // all waves done reading before next overwrite
    }

    // epilogue: gate + NT store bf16 h_out
    // C/D layout (16x16x32): col = lane&15, row = (lane>>4)*4 + reg   [m89-verified]
#pragma unroll
    for (int mt = 0; mt < 2; ++mt) {
        int rbase = m0 + wm * 32 + mt * 16 + (lane >> 4) * 4;
#pragma unroll
        for (int nt = 0; nt < 2; ++nt) {
            int cg = n0 + wn * 32 + nt * 16 + (lane & 15);
#pragma unroll
            for (int r = 0; r < 4; ++r) {
                float f  = acc[0][mt][nt][r] + biasF[nt];
                float g  = acc[1][mt][nt][r] + biasG[nt];
                float hh = acc[2][mt][nt][r] + biasH[nt];
                float gate = 1.0f / (1.0f + __expf(f));   // sigmoid(-f)
                float nh = hh + gate * (g - hh);
                __builtin_nontemporal_store(f2bf(nh),
                    hout + (size_t)(rbase + r) * HID + cg);
            }
        }
    }
}

// ---------------- final FC: out[2048][2] = h @ Wfc^T + bfc ----------------
__global__ __launch_bounds__(256) void fc_kernel(const unsigned short* __restrict__ h,
                                                 const float* __restrict__ Wfc,
                                                 const float* __restrict__ bfc,
                                                 float* __restrict__ out) {
    int row = blockIdx.x;
    int tid = threadIdx.x;
    const unsigned short* hr = h + (size_t)row * HID;
    ushort4 hv = *(const ushort4*)(hr + tid * 4);
    float h0 = bf2f(hv.x), h1 = bf2f(hv.y), h2 = bf2f(hv.z), h3 = bf2f(hv.w);
    float4 w0 = *(const float4*)(Wfc + tid * 4);
    float4 w1 = *(const float4*)(Wfc + HID + tid * 4);
    float a0 = h0 * w0.x + h1 * w0.y + h2 * w0.z + h3 * w0.w;
    float a1 = h0 * w1.x + h1 * w1.y + h2 * w1.z + h3 * w1.w;
#pragma unroll
    for (int off = 32; off > 0; off >>= 1) {
        a0 += __shfl_down(a0, off);
        a1 += __shfl_down(a1, off);
    }
    __shared__ float red[2][4];
    if ((tid & 63) == 0) { red[0][tid >> 6] = a0; red[1][tid >> 6] = a1; }
    __syncthreads();
    if (tid == 0) out[(size_t)row * 2 + 0] = red[0][0] + red[0][1] + red[0][2] + red[0][3] + bfc[0];
    if (tid == 1) out[(size_t)row * 2 + 1] = red[1][0] + red[1][1] + red[1][2] + red[1][3] + bfc[1];
}

extern "C" void kernel_launch(void* const* d_in, const int* in_sizes, int n_in,
                              void* d_out, int out_size, void* d_ws, size_t ws_size,
                              hipStream_t stream) {
    const float* x   = (const float*)d_in[0];
    const float* Wf  = (const float*)d_in[1];
    const float* bfv = (const float*)d_in[2];
    const float* Wg  = (const float*)d_in[3];
    const float* bgv = (const float*)d_in[4];
    const float* Wh  = (const float*)d_in[5];
    const float* bhv = (const float*)d_in[6];
    const float* Wfc = (const float*)d_in[7];
    const float* bfc = (const float*)d_in[8];
    float* out = (float*)d_out;

    char* ws = (char*)d_ws;
    unsigned short* Wb = (unsigned short*)ws;                       // 9.4 MB
    size_t wb_bytes = (size_t)3 * HID * CIN * 2;
    size_t h_bytes  = (size_t)BATCH * HID * 2;                      // 4 MB
    unsigned short* h0 = (unsigned short*)(ws + wb_bytes);
    unsigned short* h1 = (unsigned short*)(ws + wb_bytes + h_bytes);
    unsigned short* xbuf = (unsigned short*)(ws + wb_bytes + 2 * h_bytes);  // 128 MB
    // total ws use ~146 MB (<1 GiB)

    convert_w<<<dim3(768, 3), 256, 0, stream>>>(Wf, Wg, Wh, Wb);
    convert_x<<<32768, 256, 0, stream>>>(x, xbuf);
    (void)hipMemsetAsync(h0, 0, h_bytes, stream);                   // h_0 = 0 (capturable)

    unsigned short* bufs[2] = {h0, h1};
    for (int t = 0; t < TSEQ; ++t) {
        step_kernel<<<512, 256, 0, stream>>>(xbuf, Wb, bfv, bgv, bhv,
                                             bufs[t & 1], bufs[(t + 1) & 1], t);
    }
    // after 64 steps, final h is in bufs[0]
    fc_kernel<<<BATCH, 256, 0, stream>>>(h0, Wfc, bfc, out);
}

// Round 5
// 2242.059 us; speedup vs baseline: 3.3778x; 1.5936x over previous
//
#include <hip/hip_runtime.h>

#define BATCH 2048
#define TSEQ  64
#define DIN   512
#define HID   1024
#define CIN   1536   // DIN + HID

#define BM 128
#define BN 64
#define BK 64
#define KITERS (CIN / BK)   // 24

// LDS geometry: 8-row chunks of 128 B rows (1024 B data) + 64 B pad -> stride 1088 B.
// 1088/4 = 272 dwords, 272 % 32 = 16 -> the (row>>3) chunk step lands +16 banks, making
// b128 fragment reads exactly 8 accesses/bank (conflict-free).
#define CHUNK   1088
#define A_CHUNKS 16                    // 128 rows
#define B_CHUNKS 8                     // 64 rows per matrix
#define A_BYTES (A_CHUNKS * CHUNK)     // 17408
#define B_MAT   (B_CHUNKS * CHUNK)     // 8704
#define BUF_BYTES (A_BYTES + 3 * B_MAT) // 43520

typedef __attribute__((ext_vector_type(8))) short bf16x8;
typedef __attribute__((ext_vector_type(4))) float f32x4;
typedef __attribute__((ext_vector_type(4))) float fvec4;
typedef __attribute__((ext_vector_type(4))) unsigned int uvec4;

// RNE float -> bf16 (bits)
__device__ __forceinline__ unsigned short f2bf(float f) {
    unsigned int u = __float_as_uint(f);
    u += 0x7fffu + ((u >> 16) & 1u);
    return (unsigned short)(u >> 16);
}
__device__ __forceinline__ float bf2f(unsigned short u) {
    return __uint_as_float(((unsigned int)u) << 16);
}

// async global->LDS, 16B per lane; lane i lands at ldsbase + i*16 (wave-uniform base).
__device__ __forceinline__ void gload_lds16(const void* g, void* lds) {
    __builtin_amdgcn_global_load_lds(
        (const __attribute__((address_space(1))) void*)(uintptr_t)g,
        (__attribute__((address_space(3))) void*)(unsigned)(uintptr_t)lds,
        16, 0, 0);
}

// ---------------- weight conversion: fp32 -> bf16, 3 matrices [HID][CIN] ----------------
__global__ __launch_bounds__(256) void convert_w(const float* __restrict__ Wf,
                                                 const float* __restrict__ Wg,
                                                 const float* __restrict__ Wh,
                                                 unsigned short* __restrict__ Wb) {
    int mat = blockIdx.y;
    const float* src = (mat == 0) ? Wf : ((mat == 1) ? Wg : Wh);
    size_t base = (size_t)mat * (size_t)(HID * CIN);
    size_t idx = ((size_t)blockIdx.x * 256 + threadIdx.x) * 8;
    const fvec4* s = (const fvec4*)(src + idx);
    fvec4 a = s[0], b = s[1];
    uvec4 o;
    o.x = (unsigned)f2bf(a.x) | ((unsigned)f2bf(a.y) << 16);
    o.y = (unsigned)f2bf(a.z) | ((unsigned)f2bf(a.w) << 16);
    o.z = (unsigned)f2bf(b.x) | ((unsigned)f2bf(b.y) << 16);
    o.w = (unsigned)f2bf(b.z) | ((unsigned)f2bf(b.w) << 16);
    *(uvec4*)(Wb + base + idx) = o;
}

// ---------------- x conversion: [B][T][D] fp32 -> [T][B][D] bf16 (time-major) ----------------
__global__ __launch_bounds__(256) void convert_x(const float* __restrict__ x,
                                                 unsigned short* __restrict__ xb) {
    size_t e = ((size_t)blockIdx.x * 256 + threadIdx.x) * 8;
    int t   = (int)(e / ((size_t)BATCH * DIN));
    int rem = (int)(e % ((size_t)BATCH * DIN));
    int b = rem / DIN;
    int d = rem % DIN;
    const float* src = x + ((size_t)b * TSEQ + t) * DIN + d;
    fvec4 a = *(const fvec4*)src;
    fvec4 c = *(const fvec4*)(src + 4);
    uvec4 o;
    o.x = (unsigned)f2bf(a.x) | ((unsigned)f2bf(a.y) << 16);
    o.y = (unsigned)f2bf(a.z) | ((unsigned)f2bf(a.w) << 16);
    o.z = (unsigned)f2bf(c.x) | ((unsigned)f2bf(c.y) << 16);
    o.w = (unsigned)f2bf(c.z) | ((unsigned)f2bf(c.w) << 16);
    *(uvec4*)(xb + e) = o;
}

// ---------------- one recurrence step: fused 3xGEMM + gate ----------------
// Double-buffered LDS, DMA prefetch of tile ki+1 issued before compute(ki), ONE barrier/ki.
// 256 thr = 4 waves, wave tile 64M x 32N x 3 mats. Grid 256 = 1 block/CU.
__global__ __launch_bounds__(256, 1) void step_kernel(
    const unsigned short* __restrict__ xb,     // bf16 [TSEQ][BATCH][DIN]
    const unsigned short* __restrict__ Wb,     // bf16 [3][HID][CIN]
    const float* __restrict__ bfv,
    const float* __restrict__ bgv,
    const float* __restrict__ bhv,
    const unsigned short* __restrict__ hin,    // bf16 [BATCH][HID]
    unsigned short* __restrict__ hout,         // bf16 [BATCH][HID]
    int t)
{
    __shared__ __align__(16) char lds[2][BUF_BYTES];   // 87040 B (gfx950 GROUP pool = 160 KiB)

    const int tid  = threadIdx.x;
    const int bid  = blockIdx.x;
    // n-affinity XCD swizzle: XCD (bid&7) sees 2 n_tiles -> 1.18 MB weight slice L2-resident
    const int n_tile = ((bid & 7) << 1) | ((bid >> 3) & 1);   // 0..15
    const int m_tile = bid >> 4;                              // 0..15
    const int m0 = m_tile * BM;
    const int n0 = n_tile * BN;

    const int lane = tid & 63;
    const int wave = tid >> 6;       // 0..3
    const int wm = wave >> 1;        // 0..1 : 64-row half
    const int wn = wave & 1;         // 0..1 : 32-col half

    // DMA lane mapping inside an 8-row x 128 B chunk
    const int drow = lane >> 3;          // 0..7
    const int dcol = (lane & 7) * 8;     // elem col 0..56

    f32x4 acc[3][4][2] = {};

    float biasF[2], biasG[2], biasH[2];
#pragma unroll
    for (int nt = 0; nt < 2; ++nt) {
        int cg = n0 + wn * 32 + nt * 16 + (lane & 15);
        biasF[nt] = bfv[cg];
        biasG[nt] = bgv[cg];
        biasH[nt] = bhv[cg];
    }

    const unsigned short* xsrc = xb + (size_t)t * BATCH * DIN;

    // precomputed read offsets (bytes) for fragment loads
    int aoff[4], boff[2];
#pragma unroll
    for (int mt = 0; mt < 4; ++mt) {
        int r = wm * 64 + mt * 16 + (lane & 15);
        aoff[mt] = (r >> 3) * CHUNK + (r & 7) * 128;
    }
#pragma unroll
    for (int nt = 0; nt < 2; ++nt) {
        int n = wn * 32 + nt * 16 + (lane & 15);
        boff[nt] = (n >> 3) * CHUNK + (n & 7) * 128;
    }
    const int kboff = (lane >> 4) * 16;   // byte offset of this lane's 8-elem K-slice

    auto stage = [&](int ki, int bb) {
        char* base = lds[bb];
        const int k0 = ki * BK;
        const unsigned short* asrc;
        int astride;
        if (k0 < DIN) { asrc = xsrc + k0;        astride = DIN; }
        else          { asrc = hin + (k0 - DIN); astride = HID; }
        // A: wave w stages chunks 4w..4w+3 (rows 32w..32w+31)
#pragma unroll
        for (int c = 0; c < 4; ++c) {
            int chunk = wave * 4 + c;
            gload_lds16(asrc + (size_t)(m0 + chunk * 8 + drow) * astride + dcol,
                        base + chunk * CHUNK);
        }
        // B: per matrix, wave w stages chunks 2w..2w+1 (rows 16w..16w+15)
#pragma unroll
        for (int mat = 0; mat < 3; ++mat) {
            const unsigned short* bsrc = Wb + (size_t)mat * (HID * CIN) + k0;
#pragma unroll
            for (int c = 0; c < 2; ++c) {
                int chunk = wave * 2 + c;
                gload_lds16(bsrc + (size_t)(n0 + chunk * 8 + drow) * CIN + dcol,
                            base + A_BYTES + mat * B_MAT + chunk * CHUNK);
            }
        }
    };

    auto compute = [&](int bb) {
        const char* base = lds[bb];
#pragma unroll
        for (int ks = 0; ks < 2; ++ks) {
            const int kb = ks * 64 + kboff;   // byte offset within 128-B row
            bf16x8 af[4];
#pragma unroll
            for (int mt = 0; mt < 4; ++mt)
                af[mt] = *(const bf16x8*)(base + aoff[mt] + kb);
#pragma unroll
            for (int mat = 0; mat < 3; ++mat) {
                const char* bmat = base + A_BYTES + mat * B_MAT;
                bf16x8 b0 = *(const bf16x8*)(bmat + boff[0] + kb);
                bf16x8 b1 = *(const bf16x8*)(bmat + boff[1] + kb);
#pragma unroll
                for (int mt = 0; mt < 4; ++mt) {
                    acc[mat][mt][0] = __builtin_amdgcn_mfma_f32_16x16x32_bf16(af[mt], b0, acc[mat][mt][0], 0, 0, 0);
                    acc[mat][mt][1] = __builtin_amdgcn_mfma_f32_16x16x32_bf16(af[mt], b1, acc[mat][mt][1], 0, 0, 0);
                }
            }
        }
    };

    stage(0, 0);
    for (int ki = 0; ki < KITERS; ++ki) {
        const int bb = ki & 1;
        __syncthreads();                      // drains DMA(ki); prior compute(ki-1) readers done
        if (ki < KITERS - 1) stage(ki + 1, bb ^ 1);   // prefetch overlaps compute(ki)
        compute(bb);
    }

    // epilogue: gate + NT store bf16 h_out
    // C/D layout (16x16x32): col = lane&15, row = (lane>>4)*4 + reg   [m89-verified]
#pragma unroll
    for (int mt = 0; mt < 4; ++mt) {
        int rbase = m0 + wm * 64 + mt * 16 + (lane >> 4) * 4;
#pragma unroll
        for (int nt = 0; nt < 2; ++nt) {
            int cg = n0 + wn * 32 + nt * 16 + (lane & 15);
#pragma unroll
            for (int r = 0; r < 4; ++r) {
                float f  = acc[0][mt][nt][r] + biasF[nt];
                float g  = acc[1][mt][nt][r] + biasG[nt];
                float hh = acc[2][mt][nt][r] + biasH[nt];
                float gate = 1.0f / (1.0f + __expf(f));   // sigmoid(-f)
                float nh = hh + gate * (g - hh);
                __builtin_nontemporal_store(f2bf(nh),
                    hout + (size_t)(rbase + r) * HID + cg);
            }
        }
    }
}

// ---------------- final FC: out[2048][2] = h @ Wfc^T + bfc ----------------
__global__ __launch_bounds__(256) void fc_kernel(const unsigned short* __restrict__ h,
                                                 const float* __restrict__ Wfc,
                                                 const float* __restrict__ bfc,
                                                 float* __restrict__ out) {
    int row = blockIdx.x;
    int tid = threadIdx.x;
    const unsigned short* hr = h + (size_t)row * HID;
    ushort4 hv = *(const ushort4*)(hr + tid * 4);
    float h0 = bf2f(hv.x), h1 = bf2f(hv.y), h2 = bf2f(hv.z), h3 = bf2f(hv.w);
    float4 w0 = *(const float4*)(Wfc + tid * 4);
    float4 w1 = *(const float4*)(Wfc + HID + tid * 4);
    float a0 = h0 * w0.x + h1 * w0.y + h2 * w0.z + h3 * w0.w;
    float a1 = h0 * w1.x + h1 * w1.y + h2 * w1.z + h3 * w1.w;
#pragma unroll
    for (int off = 32; off > 0; off >>= 1) {
        a0 += __shfl_down(a0, off);
        a1 += __shfl_down(a1, off);
    }
    __shared__ float red[2][4];
    if ((tid & 63) == 0) { red[0][tid >> 6] = a0; red[1][tid >> 6] = a1; }
    __syncthreads();
    if (tid == 0) out[(size_t)row * 2 + 0] = red[0][0] + red[0][1] + red[0][2] + red[0][3] + bfc[0];
    if (tid == 1) out[(size_t)row * 2 + 1] = red[1][0] + red[1][1] + red[1][2] + red[1][3] + bfc[1];
}

extern "C" void kernel_launch(void* const* d_in, const int* in_sizes, int n_in,
                              void* d_out, int out_size, void* d_ws, size_t ws_size,
                              hipStream_t stream) {
    const float* x   = (const float*)d_in[0];
    const float* Wf  = (const float*)d_in[1];
    const float* bfv = (const float*)d_in[2];
    const float* Wg  = (const float*)d_in[3];
    const float* bgv = (const float*)d_in[4];
    const float* Wh  = (const float*)d_in[5];
    const float* bhv = (const float*)d_in[6];
    const float* Wfc = (const float*)d_in[7];
    const float* bfc = (const float*)d_in[8];
    float* out = (float*)d_out;

    char* ws = (char*)d_ws;
    unsigned short* Wb = (unsigned short*)ws;                       // 9.4 MB
    size_t wb_bytes = (size_t)3 * HID * CIN * 2;
    size_t h_bytes  = (size_t)BATCH * HID * 2;                      // 4 MB
    unsigned short* h0 = (unsigned short*)(ws + wb_bytes);
    unsigned short* h1 = (unsigned short*)(ws + wb_bytes + h_bytes);
    unsigned short* xbuf = (unsigned short*)(ws + wb_bytes + 2 * h_bytes);  // 128 MB
    // total ws use ~146 MB (harness ws ~1 GiB)

    convert_w<<<dim3(768, 3), 256, 0, stream>>>(Wf, Wg, Wh, Wb);
    convert_x<<<32768, 256, 0, stream>>>(x, xbuf);
    (void)hipMemsetAsync(h0, 0, h_bytes, stream);                   // h_0 = 0 (capturable)

    unsigned short* bufs[2] = {h0, h1};
    for (int t = 0; t < TSEQ; ++t) {
        step_kernel<<<256, 256, 0, stream>>>(xbuf, Wb, bfv, bgv, bhv,
                                             bufs[t & 1], bufs[(t + 1) & 1], t);
    }
    // after 64 steps, final h is in bufs[0]
    fc_kernel<<<BATCH, 256, 0, stream>>>(h0, Wfc, bfc, out);
}

// Round 6
// 1982.493 us; speedup vs baseline: 3.8200x; 1.1309x over previous
//
#include <hip/hip_runtime.h>

#define BATCH 2048
#define TSEQ  64
#define DIN   512
#define HID   1024
#define CIN   1536   // DIN + HID

#define BM 128
#define BN 32
#define BK 64
#define KITERS (CIN / BK)   // 24

// LDS geometry: 8-row chunks of 128 B rows (1024 B data) + 64 B pad -> stride 1088 B.
// (r>>3) chunk step lands +16 banks; row-within-chunk +0; lane quads +4; 8/8 lane split
// covers +0/+16 -> b128 fragment reads hit all 32 banks exactly 8x (conflict-free).
#define CHUNK   1088
#define A_CHUNKS 16                     // 128 rows
#define B_CHUNKS 4                      // 32 rows per matrix
#define A_BYTES (A_CHUNKS * CHUNK)      // 17408
#define B_MAT   (B_CHUNKS * CHUNK)      // 4352
#define BUF_BYTES (A_BYTES + 3 * B_MAT) // 30464  (dbuf 60928 -> 2 blocks/CU)

typedef __attribute__((ext_vector_type(8))) short bf16x8;
typedef __attribute__((ext_vector_type(4))) float f32x4;
typedef __attribute__((ext_vector_type(4))) float fvec4;
typedef __attribute__((ext_vector_type(4))) unsigned int uvec4;

// RNE float -> bf16 (bits)
__device__ __forceinline__ unsigned short f2bf(float f) {
    unsigned int u = __float_as_uint(f);
    u += 0x7fffu + ((u >> 16) & 1u);
    return (unsigned short)(u >> 16);
}
__device__ __forceinline__ float bf2f(unsigned short u) {
    return __uint_as_float(((unsigned int)u) << 16);
}

// async global->LDS, 16B per lane; lane i lands at ldsbase + i*16 (wave-uniform base).
__device__ __forceinline__ void gload_lds16(const void* g, void* lds) {
    __builtin_amdgcn_global_load_lds(
        (const __attribute__((address_space(1))) void*)(uintptr_t)g,
        (__attribute__((address_space(3))) void*)(unsigned)(uintptr_t)lds,
        16, 0, 0);
}

// ---------------- weight conversion: fp32 -> bf16, 3 matrices [HID][CIN] ----------------
__global__ __launch_bounds__(256) void convert_w(const float* __restrict__ Wf,
                                                 const float* __restrict__ Wg,
                                                 const float* __restrict__ Wh,
                                                 unsigned short* __restrict__ Wb) {
    int mat = blockIdx.y;
    const float* src = (mat == 0) ? Wf : ((mat == 1) ? Wg : Wh);
    size_t base = (size_t)mat * (size_t)(HID * CIN);
    size_t idx = ((size_t)blockIdx.x * 256 + threadIdx.x) * 8;
    const fvec4* s = (const fvec4*)(src + idx);
    fvec4 a = s[0], b = s[1];
    uvec4 o;
    o.x = (unsigned)f2bf(a.x) | ((unsigned)f2bf(a.y) << 16);
    o.y = (unsigned)f2bf(a.z) | ((unsigned)f2bf(a.w) << 16);
    o.z = (unsigned)f2bf(b.x) | ((unsigned)f2bf(b.y) << 16);
    o.w = (unsigned)f2bf(b.z) | ((unsigned)f2bf(b.w) << 16);
    *(uvec4*)(Wb + base + idx) = o;
}

// ---------------- x conversion: [B][T][D] fp32 -> [T][B][D] bf16 (time-major) ----------------
__global__ __launch_bounds__(256) void convert_x(const float* __restrict__ x,
                                                 unsigned short* __restrict__ xb) {
    size_t e = ((size_t)blockIdx.x * 256 + threadIdx.x) * 8;
    int t   = (int)(e / ((size_t)BATCH * DIN));
    int rem = (int)(e % ((size_t)BATCH * DIN));
    int b = rem / DIN;
    int d = rem % DIN;
    const float* src = x + ((size_t)b * TSEQ + t) * DIN + d;
    fvec4 a = *(const fvec4*)src;
    fvec4 c = *(const fvec4*)(src + 4);
    uvec4 o;
    o.x = (unsigned)f2bf(a.x) | ((unsigned)f2bf(a.y) << 16);
    o.y = (unsigned)f2bf(a.z) | ((unsigned)f2bf(a.w) << 16);
    o.z = (unsigned)f2bf(c.x) | ((unsigned)f2bf(c.y) << 16);
    o.w = (unsigned)f2bf(c.z) | ((unsigned)f2bf(c.w) << 16);
    *(uvec4*)(xb + e) = o;
}

// ---------------- one recurrence step: fused 3xGEMM + gate ----------------
// Double-buffered LDS with DMA prefetch, one barrier/k-iter.
// Grid 512 = 2 blocks/CU: block B's MFMAs fill block A's barrier-drain stalls (m114).
__global__ __launch_bounds__(256, 2) void step_kernel(
    const unsigned short* __restrict__ xb,     // bf16 [TSEQ][BATCH][DIN]
    const unsigned short* __restrict__ Wb,     // bf16 [3][HID][CIN]
    const float* __restrict__ bfv,
    const float* __restrict__ bgv,
    const float* __restrict__ bhv,
    const unsigned short* __restrict__ hin,    // bf16 [BATCH][HID]
    unsigned short* __restrict__ hout,         // bf16 [BATCH][HID]
    int t)
{
    __shared__ __align__(16) char lds[2][BUF_BYTES];   // 60928 B -> 2 blocks/CU (160 KiB pool)

    const int tid  = threadIdx.x;
    const int bid  = blockIdx.x;
    // n-affinity XCD swizzle: XCD (bid&7) sees n_tiles {4k..4k+3} -> 1.18 MB weight slice in L2
    const int n_tile = ((bid & 7) << 2) | ((bid >> 3) & 3);   // 0..31
    const int m_tile = bid >> 5;                              // 0..15
    const int m0 = m_tile * BM;
    const int n0 = n_tile * BN;

    const int lane = tid & 63;
    const int wave = tid >> 6;       // 0..3
    const int wm = wave >> 1;        // 0..1 : 64-row half
    const int wn = wave & 1;         // 0..1 : 16-col half

    // DMA lane mapping inside an 8-row x 128 B chunk
    const int drow = lane >> 3;          // 0..7
    const int dcol = (lane & 7) * 8;     // elem col 0..56

    f32x4 acc[3][4] = {};

    const int cg = n0 + wn * 16 + (lane & 15);
    const float biasF = bfv[cg];
    const float biasG = bgv[cg];
    const float biasH = bhv[cg];

    const unsigned short* xsrc = xb + (size_t)t * BATCH * DIN;

    // precomputed fragment read offsets (bytes)
    int aoff[4];
#pragma unroll
    for (int mt = 0; mt < 4; ++mt) {
        int r = wm * 64 + mt * 16 + (lane & 15);
        aoff[mt] = (r >> 3) * CHUNK + (r & 7) * 128;
    }
    const int nloc = wn * 16 + (lane & 15);
    const int boff = (nloc >> 3) * CHUNK + (nloc & 7) * 128;
    const int kboff = (lane >> 4) * 16;   // this lane's 8-elem K-slice within a 128-B row

    auto stage = [&](int ki, int bb) {
        char* base = lds[bb];
        const int k0 = ki * BK;
        const unsigned short* asrc;
        int astride;
        if (k0 < DIN) { asrc = xsrc + k0;        astride = DIN; }
        else          { asrc = hin + (k0 - DIN); astride = HID; }
        // A: wave w stages chunks 4w..4w+3 (rows 32w..32w+31)
#pragma unroll
        for (int c = 0; c < 4; ++c) {
            int chunk = wave * 4 + c;
            gload_lds16(asrc + (size_t)(m0 + chunk * 8 + drow) * astride + dcol,
                        base + chunk * CHUNK);
        }
        // B: 12 chunk-units (mat = u>>2, chunk = u&3); wave w stages u = 3w..3w+2
#pragma unroll
        for (int j = 0; j < 3; ++j) {
            int u = wave * 3 + j;
            int mat = u >> 2, chunk = u & 3;
            gload_lds16(Wb + (size_t)mat * (HID * CIN) + (size_t)(n0 + chunk * 8 + drow) * CIN
                           + k0 + dcol,
                        base + A_BYTES + mat * B_MAT + chunk * CHUNK);
        }
    };

    auto compute = [&](int bb) {
        const char* base = lds[bb];
#pragma unroll
        for (int ks = 0; ks < 2; ++ks) {
            const int kb = ks * 64 + kboff;
            bf16x8 af[4];
#pragma unroll
            for (int mt = 0; mt < 4; ++mt)
                af[mt] = *(const bf16x8*)(base + aoff[mt] + kb);
#pragma unroll
            for (int mat = 0; mat < 3; ++mat) {
                bf16x8 bq = *(const bf16x8*)(base + A_BYTES + mat * B_MAT + boff + kb);
#pragma unroll
                for (int mt = 0; mt < 4; ++mt)
                    acc[mat][mt] = __builtin_amdgcn_mfma_f32_16x16x32_bf16(
                        af[mt], bq, acc[mat][mt], 0, 0, 0);
            }
        }
    };

    stage(0, 0);
    for (int ki = 0; ki < KITERS; ++ki) {
        const int bb = ki & 1;
        __syncthreads();                              // drains DMA(ki); prior readers done
        if (ki < KITERS - 1) stage(ki + 1, bb ^ 1);   // prefetch overlaps compute(ki)
        compute(bb);
    }

    // epilogue: gate + NT store bf16 h_out
    // C/D layout (16x16x32): col = lane&15, row = (lane>>4)*4 + reg   [m89-verified]
#pragma unroll
    for (int mt = 0; mt < 4; ++mt) {
        int rbase = m0 + wm * 64 + mt * 16 + (lane >> 4) * 4;
#pragma unroll
        for (int r = 0; r < 4; ++r) {
            float f  = acc[0][mt][r] + biasF;
            float g  = acc[1][mt][r] + biasG;
            float hh = acc[2][mt][r] + biasH;
            float gate = 1.0f / (1.0f + __expf(f));   // sigmoid(-f)
            float nh = hh + gate * (g - hh);
            __builtin_nontemporal_store(f2bf(nh),
                hout + (size_t)(rbase + r) * HID + cg);
        }
    }
}

// ---------------- final FC: out[2048][2] = h @ Wfc^T + bfc ----------------
__global__ __launch_bounds__(256) void fc_kernel(const unsigned short* __restrict__ h,
                                                 const float* __restrict__ Wfc,
                                                 const float* __restrict__ bfc,
                                                 float* __restrict__ out) {
    int row = blockIdx.x;
    int tid = threadIdx.x;
    const unsigned short* hr = h + (size_t)row * HID;
    ushort4 hv = *(const ushort4*)(hr + tid * 4);
    float h0 = bf2f(hv.x), h1 = bf2f(hv.y), h2 = bf2f(hv.z), h3 = bf2f(hv.w);
    float4 w0 = *(const float4*)(Wfc + tid * 4);
    float4 w1 = *(const float4*)(Wfc + HID + tid * 4);
    float a0 = h0 * w0.x + h1 * w0.y + h2 * w0.z + h3 * w0.w;
    float a1 = h0 * w1.x + h1 * w1.y + h2 * w1.z + h3 * w1.w;
#pragma unroll
    for (int off = 32; off > 0; off >>= 1) {
        a0 += __shfl_down(a0, off);
        a1 += __shfl_down(a1, off);
    }
    __shared__ float red[2][4];
    if ((tid & 63) == 0) { red[0][tid >> 6] = a0; red[1][tid >> 6] = a1; }
    __syncthreads();
    if (tid == 0) out[(size_t)row * 2 + 0] = red[0][0] + red[0][1] + red[0][2] + red[0][3] + bfc[0];
    if (tid == 1) out[(size_t)row * 2 + 1] = red[1][0] + red[1][1] + red[1][2] + red[1][3] + bfc[1];
}

extern "C" void kernel_launch(void* const* d_in, const int* in_sizes, int n_in,
                              void* d_out, int out_size, void* d_ws, size_t ws_size,
                              hipStream_t stream) {
    const float* x   = (const float*)d_in[0];
    const float* Wf  = (const float*)d_in[1];
    const float* bfv = (const float*)d_in[2];
    const float* Wg  = (const float*)d_in[3];
    const float* bgv = (const float*)d_in[4];
    const float* Wh  = (const float*)d_in[5];
    const float* bhv = (const float*)d_in[6];
    const float* Wfc = (const float*)d_in[7];
    const float* bfc = (const float*)d_in[8];
    float* out = (float*)d_out;

    char* ws = (char*)d_ws;
    unsigned short* Wb = (unsigned short*)ws;                       // 9.4 MB
    size_t wb_bytes = (size_t)3 * HID * CIN * 2;
    size_t h_bytes  = (size_t)BATCH * HID * 2;                      // 4 MB
    unsigned short* h0 = (unsigned short*)(ws + wb_bytes);
    unsigned short* h1 = (unsigned short*)(ws + wb_bytes + h_bytes);
    unsigned short* xbuf = (unsigned short*)(ws + wb_bytes + 2 * h_bytes);  // 128 MB
    // total ws use ~146 MB (harness ws ~1 GiB)

    convert_w<<<dim3(768, 3), 256, 0, stream>>>(Wf, Wg, Wh, Wb);
    convert_x<<<32768, 256, 0, stream>>>(x, xbuf);
    (void)hipMemsetAsync(h0, 0, h_bytes, stream);                   // h_0 = 0 (capturable)

    unsigned short* bufs[2] = {h0, h1};
    for (int t = 0; t < TSEQ; ++t) {
        step_kernel<<<512, 256, 0, stream>>>(xbuf, Wb, bfv, bgv, bhv,
                                             bufs[t & 1], bufs[(t + 1) & 1], t);
    }
    // after 64 steps, final h is in bufs[0]
    fc_kernel<<<BATCH, 256, 0, stream>>>(h0, Wfc, bfc, out);
}